// Round 5
// baseline (234.814 us; speedup 1.0000x reference)
//
#include <hip/hip_runtime.h>
#include <hip/hip_bf16.h>
#include <math.h>

#define DIM     2048
#define LEVELS  100
#define TSN     32768
#define NBLK    1024
#define PACK_BLOCKS 200   // 8 tables x 25 level-groups (4 levels/block)

// map value in [-3,3] to level index 0..99 (round-half-even like jnp.round)
__device__ __forceinline__ int lvl100(float v) {
    float f = ((v + 3.0f) / 6.0f) * 99.0f;
    int k = (int)rintf(f);
    return min(max(k, 0), LEVELS - 1);
}

// ---------------------------------------------------------------------------
// Fused prep: blocks [0,200) pack the 8 bipolar tables into permuted sign
// words (block 0 also zeroes the global accumulator); remaining blocks
// compute per-sample indices.
// packed2[tab][level][l] (uint32): bit (4k+j) = sign(W[tab][level][256k+4l+j])
// so lane l of a wave owns dims {256k+4l+j}.
// ---------------------------------------------------------------------------
__global__ __launch_bounds__(256) void prep_k(
    const float* __restrict__ w0, const float* __restrict__ w1,
    const float* __restrict__ w2, const float* __restrict__ w3,
    const float* __restrict__ w4, const float* __restrict__ w5,
    const float* __restrict__ w6, const float* __restrict__ w7,
    const float* __restrict__ inp,
    unsigned int* __restrict__ packed2,
    unsigned long long* __restrict__ sidx,
    unsigned int* __restrict__ tidx,
    float* __restrict__ acc, int n)
{
    if (blockIdx.x < PACK_BLOCKS) {
        if (blockIdx.x == 0) {            // zero accumulator for this launch
            float2 z = make_float2(0.f, 0.f);
            ((float2*)acc)[threadIdx.x] = z;
            ((float2*)acc)[threadIdx.x + 256] = z;
            ((float2*)acc)[threadIdx.x + 512] = z;
            ((float2*)acc)[threadIdx.x + 768] = z;
        }
        int tab = blockIdx.x / 25;
        int lg  = blockIdx.x - tab * 25;
        int l   = threadIdx.x & 63;
        int level = lg * 4 + (threadIdx.x >> 6);
        const float* w;
        switch (tab) {
            case 0: w = w0; break; case 1: w = w1; break;
            case 2: w = w2; break; case 3: w = w3; break;
            case 4: w = w4; break; case 5: w = w5; break;
            case 6: w = w6; break; default: w = w7; break;
        }
        const float* base = w + (size_t)level * DIM + 4 * l;
        unsigned int word = 0;
        #pragma unroll
        for (int k = 0; k < 8; ++k) {
            float4 a = *(const float4*)(base + 256 * k);
            word |= (a.x < 0.f ? 1u : 0u) << (4 * k);
            word |= (a.y < 0.f ? 1u : 0u) << (4 * k + 1);
            word |= (a.z < 0.f ? 1u : 0u) << (4 * k + 2);
            word |= (a.w < 0.f ? 1u : 0u) << (4 * k + 3);
        }
        packed2[(tab * LEVELS + level) * 64 + l] = word;
        return;
    }
    int i = (blockIdx.x - PACK_BLOCKS) * 256 + threadIdx.x;
    if (i >= n) return;
    float t0 = inp[0];
    float ti = inp[i * 4] - t0;
    float x = inp[i * 4 + 1], y = inp[i * 4 + 2], z = inp[i * 4 + 3];
    float xc = fminf(fmaxf(x, -3.f), 3.f);
    float yc = fminf(fmaxf(y, -3.f), 3.f);
    float zc = fminf(fmaxf(z, -3.f), 3.f);
    unsigned long long ix = (unsigned long long)lvl100(xc);
    unsigned long long iy = (unsigned long long)lvl100(yc);
    unsigned long long iz = (unsigned long long)lvl100(zc);
    float mag = sqrtf((x * x + y * y) + z * z);   // unclipped, ref assoc order
    unsigned long long im = (unsigned long long)lvl100(mag);
    float jx = 0.f, jy = 0.f, jz = 0.f;
    if (i > 0) {
        float tp = inp[(i - 1) * 4] - t0;
        float dt = ti - tp;                        // dt from offset times, as ref
        jx = (x - inp[(i - 1) * 4 + 1]) / dt;
        jy = (y - inp[(i - 1) * 4 + 2]) / dt;
        jz = (z - inp[(i - 1) * 4 + 3]) / dt;
    }
    unsigned long long ixj = (unsigned long long)lvl100(fminf(fmaxf(jx, -3.f), 3.f));
    unsigned long long iyj = (unsigned long long)lvl100(fminf(fmaxf(jy, -3.f), 3.f));
    unsigned long long izj = (unsigned long long)lvl100(fminf(fmaxf(jz, -3.f), 3.f));
    float jm = sqrtf((jx * jx + jy * jy) + jz * jz);
    unsigned long long imj = (unsigned long long)lvl100(jm);
    sidx[i] = ix | (iy << 8) | (iz << 16) | (im << 24) |
              (ixj << 32) | (iyj << 40) | (izj << 48) | (imj << 56);
    float ft = (ti / 32768.0f) * 32767.0f;
    int k = (int)rintf(ft);
    tidx[i] = (unsigned int)min(max(k, 0), TSN - 1);
}

// ---------------------------------------------------------------------------
// Main: one wave covers all 2048 dims (32/lane), unconditional coalesced W_t
// row loads (pipelineable), CSA popcount of sign words, LDS block reduce,
// then one exact-integer f32 atomicAdd row per block (order-independent).
// ---------------------------------------------------------------------------
__global__ __launch_bounds__(256) void main_k(
    const float* __restrict__ Wt,
    const unsigned int* __restrict__ packed2,
    const unsigned long long* __restrict__ sidx,
    const unsigned int* __restrict__ tidx,
    float* __restrict__ acc_g, int spw, int n)
{
    __shared__ float red[4][DIM];
    const int tid = threadIdx.x;
    const int l   = tid & 63;
    const int wv  = tid >> 6;
    // XCD-bijective swizzle: 1024 blocks -> 8 XCDs x 128 contiguous chunks
    int bid = (int)((blockIdx.x & 7) * (NBLK / 8) + (blockIdx.x >> 3));
    int gw = bid * 4 + wv;
    int s0 = gw * spw;
    int s1 = min(s0 + spw, n);

    float4 acc[8];
    #pragma unroll
    for (int k = 0; k < 8; ++k) acc[k] = make_float4(0.f, 0.f, 0.f, 0.f);

    for (int s = s0; s < s1; ++s) {
        int su = __builtin_amdgcn_readfirstlane(s);
        unsigned long long sp = sidx[su];
        unsigned int ti = tidx[su];
        const float4* rowp = (const float4*)(Wt + (size_t)ti * DIM);

        unsigned int i_x  = (unsigned int)(sp)       & 0xffu;
        unsigned int i_y  = (unsigned int)(sp >> 8)  & 0xffu;
        unsigned int i_z  = (unsigned int)(sp >> 16) & 0xffu;
        unsigned int i_m  = (unsigned int)(sp >> 24) & 0xffu;
        unsigned int i_xj = (unsigned int)(sp >> 32) & 0xffu;
        unsigned int i_yj = (unsigned int)(sp >> 40) & 0xffu;
        unsigned int i_zj = (unsigned int)(sp >> 48) & 0xffu;
        unsigned int i_mj = (unsigned int)(sp >> 56) & 0xffu;

        unsigned int Bx  = packed2[(0 * LEVELS + i_x ) * 64 + l];
        unsigned int By  = packed2[(1 * LEVELS + i_y ) * 64 + l];
        unsigned int Bz  = packed2[(2 * LEVELS + i_z ) * 64 + l];
        unsigned int Bm  = packed2[(3 * LEVELS + i_m ) * 64 + l];
        unsigned int Bxj = packed2[(4 * LEVELS + i_xj) * 64 + l];
        unsigned int Byj = packed2[(5 * LEVELS + i_yj) * 64 + l];
        unsigned int Bzj = packed2[(6 * LEVELS + i_zj) * 64 + l];
        unsigned int Bmj = packed2[(7 * LEVELS + i_mj) * 64 + l];

        unsigned int e1 = Bx ^ Bm,  e2 = By ^ Bm,  e3 = Bz ^ Bm;
        unsigned int e4 = Bxj ^ Bmj, e5 = Byj ^ Bmj, e6 = Bzj ^ Bmj;
        unsigned int ta  = e1 ^ e2;
        unsigned int sA  = ta ^ e3;
        unsigned int cA  = (e1 & e2) | (e3 & ta);
        unsigned int tb2 = e4 ^ e5;
        unsigned int sB  = tb2 ^ e6;
        unsigned int cB  = (e4 & e5) | (e6 & tb2);
        unsigned int ones  = sA ^ sB;
        unsigned int cc    = sA & sB;
        unsigned int tc    = cA ^ cB;
        unsigned int twos  = tc ^ cc;
        unsigned int fours = (cA & cB) | (cc & tc);

        #pragma unroll
        for (int k = 0; k < 8; ++k) {
            float4 wt4 = rowp[64 * k + l];
            #pragma unroll
            for (int j = 0; j < 4; ++j) {
                int p = 4 * k + j;
                int v = ((ones >> p) & 1) + 2 * ((twos >> p) & 1)
                      + 4 * ((fours >> p) & 1);
                float sgn = (float)(6 - 2 * v);
                float* a = (float*)&acc[k];
                float* wf = (float*)&wt4;
                a[j] = fmaf(sgn, wf[j], a[j]);
            }
        }
    }

    float4* redw = (float4*)red[wv];
    #pragma unroll
    for (int k = 0; k < 8; ++k) redw[64 * k + l] = acc[k];
    __syncthreads();

    // threads sum the 4 wave-rows for dims [tid*8, tid*8+8), then atomicAdd.
    float4 o0 = make_float4(0.f, 0.f, 0.f, 0.f);
    float4 o1 = make_float4(0.f, 0.f, 0.f, 0.f);
    #pragma unroll
    for (int r = 0; r < 4; ++r) {
        float4 a = ((float4*)red[r])[2 * tid];
        float4 b = ((float4*)red[r])[2 * tid + 1];
        o0.x += a.x; o0.y += a.y; o0.z += a.z; o0.w += a.w;
        o1.x += b.x; o1.y += b.y; o1.z += b.z; o1.w += b.w;
    }
    float* ap = acc_g + tid * 8;
    atomicAdd(ap + 0, o0.x); atomicAdd(ap + 1, o0.y);
    atomicAdd(ap + 2, o0.z); atomicAdd(ap + 3, o0.w);
    atomicAdd(ap + 4, o1.x); atomicAdd(ap + 5, o1.y);
    atomicAdd(ap + 6, o1.z); atomicAdd(ap + 7, o1.w);
}

// ---------------------------------------------------------------------------
// Finish: tanh over the exact-integer accumulator.
// ---------------------------------------------------------------------------
__global__ __launch_bounds__(256) void tanh_k(
    const float* __restrict__ acc, float* __restrict__ out)
{
    int d = blockIdx.x * 256 + threadIdx.x;
    out[d] = tanhf(acc[d]);
}

// ---------------------------------------------------------------------------
extern "C" void kernel_launch(void* const* d_in, const int* in_sizes, int n_in,
                              void* d_out, int out_size, void* d_ws, size_t ws_size,
                              hipStream_t stream)
{
    const float* inp = (const float*)d_in[0];
    const float* wx  = (const float*)d_in[1];
    const float* wy  = (const float*)d_in[2];
    const float* wz  = (const float*)d_in[3];
    const float* wm  = (const float*)d_in[4];
    const float* wxj = (const float*)d_in[5];
    const float* wyj = (const float*)d_in[6];
    const float* wzj = (const float*)d_in[7];
    const float* wmj = (const float*)d_in[8];
    const float* wt  = (const float*)d_in[9];
    int n = in_sizes[0] / 4;

    char* ws = (char*)d_ws;
    unsigned int* packed2 = (unsigned int*)ws;        // 204800 B used
    size_t off = 256 * 1024;
    unsigned long long* sidx = (unsigned long long*)(ws + off);
    off += (size_t)n * 8;
    unsigned int* tidx = (unsigned int*)(ws + off);
    off += (size_t)n * 4;
    off = (off + 255) & ~(size_t)255;
    float* acc = (float*)(ws + off);                  // DIM floats
    off += (size_t)DIM * 4;

    int idx_blocks = (n + 255) / 256;
    hipLaunchKernelGGL(prep_k, dim3(PACK_BLOCKS + idx_blocks), dim3(256), 0, stream,
                       wx, wy, wz, wm, wxj, wyj, wzj, wmj,
                       inp, packed2, sidx, tidx, acc, n);
    int spw = (n + NBLK * 4 - 1) / (NBLK * 4);
    hipLaunchKernelGGL(main_k, dim3(NBLK), dim3(256), 0, stream,
                       wt, packed2, sidx, tidx, acc, spw, n);
    hipLaunchKernelGGL(tanh_k, dim3(DIM / 256), dim3(256), 0, stream,
                       acc, (float*)d_out);
}

// Round 6
// 78.038 us; speedup vs baseline: 3.0090x; 3.0090x over previous
//
#include <hip/hip_runtime.h>
#include <hip/hip_bf16.h>
#include <math.h>

#define DIM     2048
#define LEVELS  100
#define TSN     32768
#define NBLK    1024
#define NSPLIT  32
#define PACK_BLOCKS 200   // 8 tables x 25 level-groups (4 levels/block)

// map value in [-3,3] to level index 0..99 (round-half-even like jnp.round)
__device__ __forceinline__ int lvl100(float v) {
    float f = ((v + 3.0f) / 6.0f) * 99.0f;
    int k = (int)rintf(f);
    return min(max(k, 0), LEVELS - 1);
}

// ---------------------------------------------------------------------------
// Fused prep: blocks [0,200) pack the 8 bipolar tables into permuted sign
// words (block 0 also zeroes the reduce counters); remaining blocks compute
// per-sample indices.
// packed2[tab][level][l] (uint32): bit (4k+j) = sign(W[tab][level][256k+4l+j])
// so lane l of a wave owns dims {256k+4l+j}.
// ---------------------------------------------------------------------------
__global__ __launch_bounds__(256) void prep_k(
    const float* __restrict__ w0, const float* __restrict__ w1,
    const float* __restrict__ w2, const float* __restrict__ w3,
    const float* __restrict__ w4, const float* __restrict__ w5,
    const float* __restrict__ w6, const float* __restrict__ w7,
    const float* __restrict__ inp,
    unsigned int* __restrict__ packed2,
    unsigned long long* __restrict__ sidx,
    unsigned int* __restrict__ tidx,
    unsigned int* __restrict__ cnt, int n)
{
    if (blockIdx.x < PACK_BLOCKS) {
        if (blockIdx.x == 0 && threadIdx.x < 8) cnt[threadIdx.x] = 0u;
        int tab = blockIdx.x / 25;
        int lg  = blockIdx.x - tab * 25;
        int l   = threadIdx.x & 63;
        int level = lg * 4 + (threadIdx.x >> 6);
        const float* w;
        switch (tab) {
            case 0: w = w0; break; case 1: w = w1; break;
            case 2: w = w2; break; case 3: w = w3; break;
            case 4: w = w4; break; case 5: w = w5; break;
            case 6: w = w6; break; default: w = w7; break;
        }
        const float* base = w + (size_t)level * DIM + 4 * l;
        unsigned int word = 0;
        #pragma unroll
        for (int k = 0; k < 8; ++k) {
            float4 a = *(const float4*)(base + 256 * k);
            word |= (a.x < 0.f ? 1u : 0u) << (4 * k);
            word |= (a.y < 0.f ? 1u : 0u) << (4 * k + 1);
            word |= (a.z < 0.f ? 1u : 0u) << (4 * k + 2);
            word |= (a.w < 0.f ? 1u : 0u) << (4 * k + 3);
        }
        packed2[(tab * LEVELS + level) * 64 + l] = word;
        return;
    }
    int i = (blockIdx.x - PACK_BLOCKS) * 256 + threadIdx.x;
    if (i >= n) return;
    float t0 = inp[0];
    float ti = inp[i * 4] - t0;
    float x = inp[i * 4 + 1], y = inp[i * 4 + 2], z = inp[i * 4 + 3];
    float xc = fminf(fmaxf(x, -3.f), 3.f);
    float yc = fminf(fmaxf(y, -3.f), 3.f);
    float zc = fminf(fmaxf(z, -3.f), 3.f);
    unsigned long long ix = (unsigned long long)lvl100(xc);
    unsigned long long iy = (unsigned long long)lvl100(yc);
    unsigned long long iz = (unsigned long long)lvl100(zc);
    float mag = sqrtf((x * x + y * y) + z * z);   // unclipped, ref assoc order
    unsigned long long im = (unsigned long long)lvl100(mag);
    float jx = 0.f, jy = 0.f, jz = 0.f;
    if (i > 0) {
        float tp = inp[(i - 1) * 4] - t0;
        float dt = ti - tp;                        // dt from offset times, as ref
        jx = (x - inp[(i - 1) * 4 + 1]) / dt;
        jy = (y - inp[(i - 1) * 4 + 2]) / dt;
        jz = (z - inp[(i - 1) * 4 + 3]) / dt;
    }
    unsigned long long ixj = (unsigned long long)lvl100(fminf(fmaxf(jx, -3.f), 3.f));
    unsigned long long iyj = (unsigned long long)lvl100(fminf(fmaxf(jy, -3.f), 3.f));
    unsigned long long izj = (unsigned long long)lvl100(fminf(fmaxf(jz, -3.f), 3.f));
    float jm = sqrtf((jx * jx + jy * jy) + jz * jz);
    unsigned long long imj = (unsigned long long)lvl100(jm);
    sidx[i] = ix | (iy << 8) | (iz << 16) | (im << 24) |
              (ixj << 32) | (iyj << 40) | (izj << 48) | (imj << 56);
    float ft = (ti / 32768.0f) * 32767.0f;
    int k = (int)rintf(ft);
    tidx[i] = (unsigned int)min(max(k, 0), TSN - 1);
}

// ---------------------------------------------------------------------------
// Main (round-3 known-good): one wave covers all 2048 dims (32/lane).
// Unconditional coalesced W_t row loads (pipelineable), CSA popcount of sign
// words, LDS block reduce -> one partial row per block. Exact integer sums.
// ---------------------------------------------------------------------------
__global__ __launch_bounds__(256) void main_k(
    const float* __restrict__ Wt,
    const unsigned int* __restrict__ packed2,
    const unsigned long long* __restrict__ sidx,
    const unsigned int* __restrict__ tidx,
    float* __restrict__ partials, int spw, int n)
{
    __shared__ float red[4][DIM];
    const int tid = threadIdx.x;
    const int l   = tid & 63;
    const int wv  = tid >> 6;
    int gw = blockIdx.x * 4 + wv;
    int s0 = gw * spw;
    int s1 = min(s0 + spw, n);

    float4 acc[8];
    #pragma unroll
    for (int k = 0; k < 8; ++k) acc[k] = make_float4(0.f, 0.f, 0.f, 0.f);

    for (int s = s0; s < s1; ++s) {
        int su = __builtin_amdgcn_readfirstlane(s);
        unsigned long long sp = sidx[su];
        unsigned int ti = tidx[su];
        const float4* rowp = (const float4*)(Wt + (size_t)ti * DIM);

        unsigned int i_x  = (unsigned int)(sp)       & 0xffu;
        unsigned int i_y  = (unsigned int)(sp >> 8)  & 0xffu;
        unsigned int i_z  = (unsigned int)(sp >> 16) & 0xffu;
        unsigned int i_m  = (unsigned int)(sp >> 24) & 0xffu;
        unsigned int i_xj = (unsigned int)(sp >> 32) & 0xffu;
        unsigned int i_yj = (unsigned int)(sp >> 40) & 0xffu;
        unsigned int i_zj = (unsigned int)(sp >> 48) & 0xffu;
        unsigned int i_mj = (unsigned int)(sp >> 56) & 0xffu;

        unsigned int Bx  = packed2[(0 * LEVELS + i_x ) * 64 + l];
        unsigned int By  = packed2[(1 * LEVELS + i_y ) * 64 + l];
        unsigned int Bz  = packed2[(2 * LEVELS + i_z ) * 64 + l];
        unsigned int Bm  = packed2[(3 * LEVELS + i_m ) * 64 + l];
        unsigned int Bxj = packed2[(4 * LEVELS + i_xj) * 64 + l];
        unsigned int Byj = packed2[(5 * LEVELS + i_yj) * 64 + l];
        unsigned int Bzj = packed2[(6 * LEVELS + i_zj) * 64 + l];
        unsigned int Bmj = packed2[(7 * LEVELS + i_mj) * 64 + l];

        unsigned int e1 = Bx ^ Bm,  e2 = By ^ Bm,  e3 = Bz ^ Bm;
        unsigned int e4 = Bxj ^ Bmj, e5 = Byj ^ Bmj, e6 = Bzj ^ Bmj;
        unsigned int ta  = e1 ^ e2;
        unsigned int sA  = ta ^ e3;
        unsigned int cA  = (e1 & e2) | (e3 & ta);
        unsigned int tb2 = e4 ^ e5;
        unsigned int sB  = tb2 ^ e6;
        unsigned int cB  = (e4 & e5) | (e6 & tb2);
        unsigned int ones  = sA ^ sB;
        unsigned int cc    = sA & sB;
        unsigned int tc    = cA ^ cB;
        unsigned int twos  = tc ^ cc;
        unsigned int fours = (cA & cB) | (cc & tc);

        #pragma unroll
        for (int k = 0; k < 8; ++k) {
            float4 wt4 = rowp[64 * k + l];
            #pragma unroll
            for (int j = 0; j < 4; ++j) {
                int p = 4 * k + j;
                int v = ((ones >> p) & 1) + 2 * ((twos >> p) & 1)
                      + 4 * ((fours >> p) & 1);
                float sgn = (float)(6 - 2 * v);
                float* a = (float*)&acc[k];
                float* wf = (float*)&wt4;
                a[j] = fmaf(sgn, wf[j], a[j]);
            }
        }
    }

    float4* redw = (float4*)red[wv];
    #pragma unroll
    for (int k = 0; k < 8; ++k) redw[64 * k + l] = acc[k];
    __syncthreads();

    float4 o0 = make_float4(0.f, 0.f, 0.f, 0.f);
    float4 o1 = make_float4(0.f, 0.f, 0.f, 0.f);
    #pragma unroll
    for (int r = 0; r < 4; ++r) {
        float4 a = ((float4*)red[r])[2 * tid];
        float4 b = ((float4*)red[r])[2 * tid + 1];
        o0.x += a.x; o0.y += a.y; o0.z += a.z; o0.w += a.w;
        o1.x += b.x; o1.y += b.y; o1.z += b.z; o1.w += b.w;
    }
    float4* pout = (float4*)(partials + (size_t)blockIdx.x * DIM + tid * 8);
    pout[0] = o0;
    pout[1] = o1;
}

// ---------------------------------------------------------------------------
// Fused reduce: grid (8, NSPLIT). Block (x,y) sums its row-slice for its
// 256 dims into partial2; the LAST block per column-strip (device-scope
// counter) sums partial2 and applies tanh. Sums are exact integers, so
// any completion order gives identical output. cnt zeroed by prep_k.
// ---------------------------------------------------------------------------
__global__ __launch_bounds__(256) void reduce_k(
    const float* __restrict__ partials, float* __restrict__ partial2,
    unsigned int* __restrict__ cnt, float* __restrict__ out,
    int rows_per, int nblk)
{
    int x = blockIdx.x, y = blockIdx.y;
    int d = x * 256 + threadIdx.x;
    int r0 = y * rows_per;
    int r1 = min(r0 + rows_per, nblk);
    float s = 0.f;
    for (int b = r0; b < r1; ++b) s += partials[(size_t)b * DIM + d];
    partial2[(size_t)y * DIM + d] = s;
    __threadfence();                       // release this thread's store
    __syncthreads();
    __shared__ unsigned int so;
    if (threadIdx.x == 0) so = atomicAdd(&cnt[x], 1u);
    __syncthreads();
    if (so == gridDim.y - 1) {             // last block for this strip
        __threadfence();                   // acquire
        float t = 0.f;
        for (int r = 0; r < (int)gridDim.y; ++r)
            t += partial2[(size_t)r * DIM + d];
        out[d] = tanhf(t);
    }
}

// ---------------------------------------------------------------------------
extern "C" void kernel_launch(void* const* d_in, const int* in_sizes, int n_in,
                              void* d_out, int out_size, void* d_ws, size_t ws_size,
                              hipStream_t stream)
{
    const float* inp = (const float*)d_in[0];
    const float* wx  = (const float*)d_in[1];
    const float* wy  = (const float*)d_in[2];
    const float* wz  = (const float*)d_in[3];
    const float* wm  = (const float*)d_in[4];
    const float* wxj = (const float*)d_in[5];
    const float* wyj = (const float*)d_in[6];
    const float* wzj = (const float*)d_in[7];
    const float* wmj = (const float*)d_in[8];
    const float* wt  = (const float*)d_in[9];
    int n = in_sizes[0] / 4;

    char* ws = (char*)d_ws;
    unsigned int* packed2 = (unsigned int*)ws;        // 204800 B used
    size_t off = 256 * 1024;
    unsigned long long* sidx = (unsigned long long*)(ws + off);
    off += (size_t)n * 8;
    unsigned int* tidx = (unsigned int*)(ws + off);
    off += (size_t)n * 4;
    off = (off + 255) & ~(size_t)255;

    float* partial2 = (float*)(ws + off);             // NSPLIT x DIM
    off += (size_t)NSPLIT * DIM * 4;
    unsigned int* cnt = (unsigned int*)(ws + off);    // 8 counters
    off += 256;

    int nblk = NBLK;
    while (nblk > 32 && off + (size_t)nblk * DIM * 4 > ws_size) nblk >>= 1;
    float* partials = (float*)(ws + off);

    int idx_blocks = (n + 255) / 256;
    hipLaunchKernelGGL(prep_k, dim3(PACK_BLOCKS + idx_blocks), dim3(256), 0, stream,
                       wx, wy, wz, wm, wxj, wyj, wzj, wmj,
                       inp, packed2, sidx, tidx, cnt, n);
    int spw = (n + nblk * 4 - 1) / (nblk * 4);
    hipLaunchKernelGGL(main_k, dim3(nblk), dim3(256), 0, stream,
                       wt, packed2, sidx, tidx, partials, spw, n);
    int rows_per = (nblk + NSPLIT - 1) / NSPLIT;
    hipLaunchKernelGGL(reduce_k, dim3(DIM / 256, NSPLIT), dim3(256), 0, stream,
                       partials, partial2, cnt, (float*)d_out, rows_per, nblk);
}

// Round 7
// 55.332 us; speedup vs baseline: 4.2437x; 1.4104x over previous
//
#include <hip/hip_runtime.h>
#include <hip/hip_bf16.h>
#include <math.h>

#define DIM     2048
#define LEVELS  100
#define TSN     32768
#define NBLK    1024
#define NSPLIT  32
#define PACK_BLOCKS 200   // 8 tables x 25 level-groups (4 levels/block)

// map value in [-3,3] to level index 0..99 (round-half-even like jnp.round)
__device__ __forceinline__ int lvl100(float v) {
    float f = ((v + 3.0f) / 6.0f) * 99.0f;
    int k = (int)rintf(f);
    return min(max(k, 0), LEVELS - 1);
}

// ---------------------------------------------------------------------------
// Fused prep: blocks [0,200) pack the 8 bipolar tables into permuted sign
// words; remaining blocks compute per-sample indices.
// packed2[tab][level][l] (uint32): bit (4k+j) = sign(W[tab][level][256k+4l+j])
// so lane l of a wave owns dims {256k+4l+j}.
// ---------------------------------------------------------------------------
__global__ __launch_bounds__(256) void prep_k(
    const float* __restrict__ w0, const float* __restrict__ w1,
    const float* __restrict__ w2, const float* __restrict__ w3,
    const float* __restrict__ w4, const float* __restrict__ w5,
    const float* __restrict__ w6, const float* __restrict__ w7,
    const float* __restrict__ inp,
    unsigned int* __restrict__ packed2,
    unsigned long long* __restrict__ sidx,
    unsigned int* __restrict__ tidx, int n)
{
    if (blockIdx.x < PACK_BLOCKS) {
        int tab = blockIdx.x / 25;
        int lg  = blockIdx.x - tab * 25;
        int l   = threadIdx.x & 63;
        int level = lg * 4 + (threadIdx.x >> 6);
        const float* w;
        switch (tab) {
            case 0: w = w0; break; case 1: w = w1; break;
            case 2: w = w2; break; case 3: w = w3; break;
            case 4: w = w4; break; case 5: w = w5; break;
            case 6: w = w6; break; default: w = w7; break;
        }
        const float* base = w + (size_t)level * DIM + 4 * l;
        unsigned int word = 0;
        #pragma unroll
        for (int k = 0; k < 8; ++k) {
            float4 a = *(const float4*)(base + 256 * k);
            word |= (a.x < 0.f ? 1u : 0u) << (4 * k);
            word |= (a.y < 0.f ? 1u : 0u) << (4 * k + 1);
            word |= (a.z < 0.f ? 1u : 0u) << (4 * k + 2);
            word |= (a.w < 0.f ? 1u : 0u) << (4 * k + 3);
        }
        packed2[(tab * LEVELS + level) * 64 + l] = word;
        return;
    }
    int i = (blockIdx.x - PACK_BLOCKS) * 256 + threadIdx.x;
    if (i >= n) return;
    float t0 = inp[0];
    float ti = inp[i * 4] - t0;
    float x = inp[i * 4 + 1], y = inp[i * 4 + 2], z = inp[i * 4 + 3];
    float xc = fminf(fmaxf(x, -3.f), 3.f);
    float yc = fminf(fmaxf(y, -3.f), 3.f);
    float zc = fminf(fmaxf(z, -3.f), 3.f);
    unsigned long long ix = (unsigned long long)lvl100(xc);
    unsigned long long iy = (unsigned long long)lvl100(yc);
    unsigned long long iz = (unsigned long long)lvl100(zc);
    float mag = sqrtf((x * x + y * y) + z * z);   // unclipped, ref assoc order
    unsigned long long im = (unsigned long long)lvl100(mag);
    float jx = 0.f, jy = 0.f, jz = 0.f;
    if (i > 0) {
        float tp = inp[(i - 1) * 4] - t0;
        float dt = ti - tp;                        // dt from offset times, as ref
        jx = (x - inp[(i - 1) * 4 + 1]) / dt;
        jy = (y - inp[(i - 1) * 4 + 2]) / dt;
        jz = (z - inp[(i - 1) * 4 + 3]) / dt;
    }
    unsigned long long ixj = (unsigned long long)lvl100(fminf(fmaxf(jx, -3.f), 3.f));
    unsigned long long iyj = (unsigned long long)lvl100(fminf(fmaxf(jy, -3.f), 3.f));
    unsigned long long izj = (unsigned long long)lvl100(fminf(fmaxf(jz, -3.f), 3.f));
    float jm = sqrtf((jx * jx + jy * jy) + jz * jz);
    unsigned long long imj = (unsigned long long)lvl100(jm);
    sidx[i] = ix | (iy << 8) | (iz << 16) | (im << 24) |
              (ixj << 32) | (iyj << 40) | (izj << 48) | (imj << 56);
    float ft = (ti / 32768.0f) * 32767.0f;
    int k = (int)rintf(ft);
    tidx[i] = (unsigned int)min(max(k, 0), TSN - 1);
}

// ---------------------------------------------------------------------------
// Main (round-3 structure): one wave covers all 2048 dims (32/lane).
// Unconditional coalesced W_t row loads, CSA popcount of sign words,
// LDS block reduce -> one partial row per block. Exact integer sums.
// Unroll-2 pairs two samples' independent loads for memory-level parallelism.
// ---------------------------------------------------------------------------
__global__ __launch_bounds__(256) void main_k(
    const float* __restrict__ Wt,
    const unsigned int* __restrict__ packed2,
    const unsigned long long* __restrict__ sidx,
    const unsigned int* __restrict__ tidx,
    float* __restrict__ partials, int spw, int n)
{
    __shared__ float red[4][DIM];
    const int tid = threadIdx.x;
    const int l   = tid & 63;
    const int wv  = tid >> 6;
    int gw = blockIdx.x * 4 + wv;
    int s0 = gw * spw;
    int s1 = min(s0 + spw, n);

    float4 acc[8];
    #pragma unroll
    for (int k = 0; k < 8; ++k) acc[k] = make_float4(0.f, 0.f, 0.f, 0.f);

    #pragma unroll 2
    for (int s = s0; s < s1; ++s) {
        int su = __builtin_amdgcn_readfirstlane(s);
        unsigned long long sp = sidx[su];
        unsigned int ti = tidx[su];
        const float4* rowp = (const float4*)(Wt + (size_t)ti * DIM);

        unsigned int i_x  = (unsigned int)(sp)       & 0xffu;
        unsigned int i_y  = (unsigned int)(sp >> 8)  & 0xffu;
        unsigned int i_z  = (unsigned int)(sp >> 16) & 0xffu;
        unsigned int i_m  = (unsigned int)(sp >> 24) & 0xffu;
        unsigned int i_xj = (unsigned int)(sp >> 32) & 0xffu;
        unsigned int i_yj = (unsigned int)(sp >> 40) & 0xffu;
        unsigned int i_zj = (unsigned int)(sp >> 48) & 0xffu;
        unsigned int i_mj = (unsigned int)(sp >> 56) & 0xffu;

        unsigned int Bx  = packed2[(0 * LEVELS + i_x ) * 64 + l];
        unsigned int By  = packed2[(1 * LEVELS + i_y ) * 64 + l];
        unsigned int Bz  = packed2[(2 * LEVELS + i_z ) * 64 + l];
        unsigned int Bm  = packed2[(3 * LEVELS + i_m ) * 64 + l];
        unsigned int Bxj = packed2[(4 * LEVELS + i_xj) * 64 + l];
        unsigned int Byj = packed2[(5 * LEVELS + i_yj) * 64 + l];
        unsigned int Bzj = packed2[(6 * LEVELS + i_zj) * 64 + l];
        unsigned int Bmj = packed2[(7 * LEVELS + i_mj) * 64 + l];

        unsigned int e1 = Bx ^ Bm,  e2 = By ^ Bm,  e3 = Bz ^ Bm;
        unsigned int e4 = Bxj ^ Bmj, e5 = Byj ^ Bmj, e6 = Bzj ^ Bmj;
        unsigned int ta  = e1 ^ e2;
        unsigned int sA  = ta ^ e3;
        unsigned int cA  = (e1 & e2) | (e3 & ta);
        unsigned int tb2 = e4 ^ e5;
        unsigned int sB  = tb2 ^ e6;
        unsigned int cB  = (e4 & e5) | (e6 & tb2);
        unsigned int ones  = sA ^ sB;
        unsigned int cc    = sA & sB;
        unsigned int tc    = cA ^ cB;
        unsigned int twos  = tc ^ cc;
        unsigned int fours = (cA & cB) | (cc & tc);

        #pragma unroll
        for (int k = 0; k < 8; ++k) {
            float4 wt4 = rowp[64 * k + l];
            #pragma unroll
            for (int j = 0; j < 4; ++j) {
                int p = 4 * k + j;
                int v = ((ones >> p) & 1) + 2 * ((twos >> p) & 1)
                      + 4 * ((fours >> p) & 1);
                float sgn = (float)(6 - 2 * v);
                float* a = (float*)&acc[k];
                float* wf = (float*)&wt4;
                a[j] = fmaf(sgn, wf[j], a[j]);
            }
        }
    }

    float4* redw = (float4*)red[wv];
    #pragma unroll
    for (int k = 0; k < 8; ++k) redw[64 * k + l] = acc[k];
    __syncthreads();

    float4 o0 = make_float4(0.f, 0.f, 0.f, 0.f);
    float4 o1 = make_float4(0.f, 0.f, 0.f, 0.f);
    #pragma unroll
    for (int r = 0; r < 4; ++r) {
        float4 a = ((float4*)red[r])[2 * tid];
        float4 b = ((float4*)red[r])[2 * tid + 1];
        o0.x += a.x; o0.y += a.y; o0.z += a.z; o0.w += a.w;
        o1.x += b.x; o1.y += b.y; o1.z += b.z; o1.w += b.w;
    }
    float4* pout = (float4*)(partials + (size_t)blockIdx.x * DIM + tid * 8);
    pout[0] = o0;
    pout[1] = o1;
}

// ---------------------------------------------------------------------------
// Stage-1 reduce: grid (DIM/256, NSPLIT), coalesced row sums.
// ---------------------------------------------------------------------------
__global__ __launch_bounds__(256) void reduce1_k(
    const float* __restrict__ partials, float* __restrict__ partial2,
    int rows_per, int nblk)
{
    int d = blockIdx.x * 256 + threadIdx.x;
    int r0 = blockIdx.y * rows_per;
    int r1 = min(r0 + rows_per, nblk);
    float s = 0.f;
    for (int b = r0; b < r1; ++b) s += partials[(size_t)b * DIM + d];
    partial2[(size_t)blockIdx.y * DIM + d] = s;
}

// ---------------------------------------------------------------------------
// Stage-2 reduce + tanh.
// ---------------------------------------------------------------------------
__global__ __launch_bounds__(256) void reduce2_k(
    const float* __restrict__ partial2, float* __restrict__ out)
{
    int d = blockIdx.x * 256 + threadIdx.x;
    float s = 0.f;
    #pragma unroll
    for (int b = 0; b < NSPLIT; ++b) s += partial2[(size_t)b * DIM + d];
    out[d] = tanhf(s);
}

// ---------------------------------------------------------------------------
extern "C" void kernel_launch(void* const* d_in, const int* in_sizes, int n_in,
                              void* d_out, int out_size, void* d_ws, size_t ws_size,
                              hipStream_t stream)
{
    const float* inp = (const float*)d_in[0];
    const float* wx  = (const float*)d_in[1];
    const float* wy  = (const float*)d_in[2];
    const float* wz  = (const float*)d_in[3];
    const float* wm  = (const float*)d_in[4];
    const float* wxj = (const float*)d_in[5];
    const float* wyj = (const float*)d_in[6];
    const float* wzj = (const float*)d_in[7];
    const float* wmj = (const float*)d_in[8];
    const float* wt  = (const float*)d_in[9];
    int n = in_sizes[0] / 4;

    char* ws = (char*)d_ws;
    unsigned int* packed2 = (unsigned int*)ws;        // 204800 B used
    size_t off = 256 * 1024;
    unsigned long long* sidx = (unsigned long long*)(ws + off);
    off += (size_t)n * 8;
    unsigned int* tidx = (unsigned int*)(ws + off);
    off += (size_t)n * 4;
    off = (off + 255) & ~(size_t)255;

    float* partial2 = (float*)(ws + off);             // NSPLIT x DIM
    off += (size_t)NSPLIT * DIM * 4;

    int nblk = NBLK;
    while (nblk > 32 && off + (size_t)nblk * DIM * 4 > ws_size) nblk >>= 1;
    float* partials = (float*)(ws + off);

    int idx_blocks = (n + 255) / 256;
    hipLaunchKernelGGL(prep_k, dim3(PACK_BLOCKS + idx_blocks), dim3(256), 0, stream,
                       wx, wy, wz, wm, wxj, wyj, wzj, wmj,
                       inp, packed2, sidx, tidx, n);
    int spw = (n + nblk * 4 - 1) / (nblk * 4);
    hipLaunchKernelGGL(main_k, dim3(nblk), dim3(256), 0, stream,
                       wt, packed2, sidx, tidx, partials, spw, n);
    int rows_per = (nblk + NSPLIT - 1) / NSPLIT;
    hipLaunchKernelGGL(reduce1_k, dim3(DIM / 256, NSPLIT), dim3(256), 0, stream,
                       partials, partial2, rows_per, nblk);
    hipLaunchKernelGGL(reduce2_k, dim3(DIM / 256), dim3(256), 0, stream,
                       partial2, (float*)d_out);
}